// Round 4
// baseline (112.709 us; speedup 1.0000x reference)
//
#include <hip/hip_runtime.h>
#include <float.h>
#include <math.h>

#define BATCH 4
#define NPTS 4096
#define SEG 8
#define TPTS (NPTS / SEG)        // 512 targets/segment -> 8 KB LDS (float4 w/ |t|^2)
#define BLK 256
#define QCH 4                    // queries per thread, chamfer
#define H2 (0.03f * 0.03f)
#define RADIUS_C 0.07f
#define EPS_C 1e-12f
#define NQ (BATCH * NPTS)        // 16384
#define NCH (2 * NQ)             // 32768 chamfer (type,b,q) rows

// d_ws layout:
//   hdr    : float accum[2] + uint cnt + pad (16 B)     @ 0   (zeroed by partial blk0)
//   minseg : float [SEG][NCH]                (1 MB)     @ 16
//   top4   : float4[SEG][NQ]                 (2 MB)     @ 16 + 1 MB
//
// d2 = (|t|^2 - 2 q.t) + |q|^2 (reference's own expansion). Inner loops track
// h = |t|^2 - 2 q.t via n = -2q; +|q|^2 added at the partial store.
// Chamfer threads own QCH=4 queries so one ds_read_b128 (broadcast) feeds
// 16 VALU ops -> VALU-bound, not LDS-pipe-bound (R2 post-mortem).

// blockIdx.z = type*4 + b; type: 0 pred->gt, 1 gt->pred, 2 repulsion pred->pred
// grid.x = 16; chamfer blocks use x < NPTS/(BLK*QCH) = 4, rest return.
__global__ __launch_bounds__(BLK) void partial_kernel(
    const float* __restrict__ pred, const float* __restrict__ gt,
    float* __restrict__ minseg, float4* __restrict__ top4,
    unsigned int* __restrict__ hdr)
{
    __shared__ float4 s[TPTS];   // (x, y, z, |t|^2)

    if (blockIdx.x == 0 && blockIdx.y == 0 && blockIdx.z == 0 && threadIdx.x < 4)
        hdr[threadIdx.x] = 0u;   // zero accum[2]+cnt for merge (kernel-boundary visible)

    const int type = blockIdx.z >> 2;
    const int b    = blockIdx.z & 3;
    const int seg  = blockIdx.y;

    if (type < 2 && blockIdx.x >= NPTS / (BLK * QCH)) return;  // block-uniform

    const float* qbase = (type == 1) ? gt : pred;
    const float* tbase = (type == 0) ? gt : pred;

    // stage segment: 512 points, 2 per thread, |t|^2 computed on the fly
    {
        const float2* g2 = (const float2*)(tbase + ((size_t)b * NPTS + seg * TPTS) * 3);
        float2 a = g2[3 * threadIdx.x + 0];
        float2 c = g2[3 * threadIdx.x + 1];
        float2 e = g2[3 * threadIdx.x + 2];
        float t20 = fmaf(a.x, a.x, fmaf(a.y, a.y, c.x * c.x));
        float t21 = fmaf(c.y, c.y, fmaf(e.x, e.x, e.y * e.y));
        s[2 * threadIdx.x + 0] = make_float4(a.x, a.y, c.x, t20);
        s[2 * threadIdx.x + 1] = make_float4(c.y, e.x, e.y, t21);
    }
    __syncthreads();

    if (type < 2) {
        // QCH=4 queries per thread, stride BLK
        const int q0 = blockIdx.x * (BLK * QCH) + threadIdx.x;
        float nx[QCH], ny[QCH], nz[QCH], q2[QCH], mn[QCH];
        #pragma unroll
        for (int k = 0; k < QCH; ++k) {
            const float* q = qbase + ((size_t)b * NPTS + q0 + k * BLK) * 3;
            float qx = q[0], qy = q[1], qz = q[2];
            q2[k] = fmaf(qx, qx, fmaf(qy, qy, qz * qz));
            nx[k] = -2.f * qx; ny[k] = -2.f * qy; nz[k] = -2.f * qz;
            mn[k] = FLT_MAX;
        }
        #pragma unroll 2
        for (int j = 0; j < TPTS; ++j) {
            float4 t = s[j];
            #pragma unroll
            for (int k = 0; k < QCH; ++k)
                mn[k] = fminf(mn[k],
                    fmaf(nx[k], t.x, fmaf(ny[k], t.y, fmaf(nz[k], t.z, t.w))));
        }
        float* row = minseg + (size_t)seg * NCH + (type * BATCH + b) * NPTS;
        #pragma unroll
        for (int k = 0; k < QCH; ++k)
            row[q0 + k * BLK] = mn[k] + q2[k];
    } else {
        const int qi = blockIdx.x * BLK + threadIdx.x;
        const float* q = qbase + ((size_t)b * NPTS + qi) * 3;
        const float qx = q[0], qy = q[1], qz = q[2];
        const float q2 = fmaf(qx, qx, fmaf(qy, qy, qz * qz));
        const float nx = -2.f * qx, ny = -2.f * qy, nz = -2.f * qz;

        float m0 = FLT_MAX, m1 = FLT_MAX, m2 = FLT_MAX, m3 = FLT_MAX;
        const int base = seg * TPTS;
        #pragma unroll 4
        for (int j = 0; j < TPTS; ++j) {
            float4 t = s[j];
            float h = fmaf(nx, t.x, fmaf(ny, t.y, fmaf(nz, t.z, t.w)));
            h = (base + j == qi) ? FLT_MAX : h;            // exclude self
            float n0 = fminf(m0, h);  float u0 = fmaxf(m0, h);
            float n1 = fminf(m1, u0); float u1 = fmaxf(m1, u0);
            float n2 = fminf(m2, u1); float u2 = fmaxf(m2, u1);
            float n3 = fminf(m3, u2);
            m0 = n0; m1 = n1; m2 = n2; m3 = n3;
        }
        top4[(size_t)seg * NQ + b * NPTS + qi] =
            make_float4(m0 + q2, m1 + q2, m2 + q2, m3 + q2);
    }
}

// 192 blocks: [0,128) chamfer sum; [128,192) repulsion merge+eval.
// Last block (fenced atomic counter) finalizes both outputs.
__global__ __launch_bounds__(BLK) void merge_kernel(
    const float* __restrict__ minseg, const float4* __restrict__ top4,
    unsigned int* __restrict__ hdr, float* __restrict__ out)
{
    __shared__ float warr[BLK / 64];
    float contrib;
    int which;
    if (blockIdx.x < NCH / BLK) {
        int i = blockIdx.x * BLK + threadIdx.x;            // [0, 32768)
        float m = minseg[i];
        #pragma unroll
        for (int sg = 1; sg < SEG; ++sg)
            m = fminf(m, minseg[(size_t)sg * NCH + i]);
        contrib = fmaxf(m, 0.f);                           // clamp as in reference
        which = 0;
    } else {
        int i = (blockIdx.x - NCH / BLK) * BLK + threadIdx.x;  // [0, 16384)
        float m0 = FLT_MAX, m1 = FLT_MAX, m2 = FLT_MAX, m3 = FLT_MAX;
        #pragma unroll
        for (int sg = 0; sg < SEG; ++sg) {
            float4 v = top4[(size_t)sg * NQ + i];
            const float vals[4] = {v.x, v.y, v.z, v.w};
            #pragma unroll
            for (int k = 0; k < 4; ++k) {
                float h = vals[k];
                float n0 = fminf(m0, h);  float u0 = fmaxf(m0, h);
                float n1 = fminf(m1, u0); float u1 = fmaxf(m1, u0);
                float n2 = fminf(m2, u1); float u2 = fmaxf(m2, u1);
                float n3 = fminf(m3, u2);
                m0 = n0; m1 = n1; m2 = n2; m3 = n3;
            }
        }
        contrib = 0.f;
        const float ms[4] = {m0, m1, m2, m3};
        #pragma unroll
        for (int k = 0; k < 4; ++k) {
            float d2 = fmaxf(ms[k], EPS_C);
            float d  = sqrtf(d2);
            contrib += (RADIUS_C - d) * expf(-d2 * (1.f / H2));
        }
        which = 1;
    }
    #pragma unroll
    for (int off = 32; off > 0; off >>= 1)
        contrib += __shfl_down(contrib, off, 64);
    if ((threadIdx.x & 63) == 0) warr[threadIdx.x >> 6] = contrib;
    __syncthreads();
    if (threadIdx.x == 0) {
        float bs = warr[0] + warr[1] + warr[2] + warr[3];
        float* accum = (float*)hdr;
        atomicAdd(&accum[which], bs);
        __threadfence();
        unsigned int old = atomicAdd(&hdr[2], 1u);
        if (old == 191u) {                                  // last block finalizes
            float a0 = atomicAdd(&accum[0], 0.f);           // coherent read
            float a1 = atomicAdd(&accum[1], 0.f);
            out[0] = 100.f * a0 * (1.f / NQ);
            out[1] = a1 * (1.f / (NQ * 4));
        }
    }
}

extern "C" void kernel_launch(void* const* d_in, const int* in_sizes, int n_in,
                              void* d_out, int out_size, void* d_ws, size_t ws_size,
                              hipStream_t stream)
{
    const float* pred = (const float*)d_in[0];
    const float* gt   = (const float*)d_in[1];

    unsigned int* hdr    = (unsigned int*)d_ws;
    float*        minseg = (float*)((char*)d_ws + 16);
    float4*       top4   = (float4*)((char*)d_ws + 16 + (size_t)SEG * NCH * sizeof(float));

    dim3 grid(NPTS / BLK, SEG, 3 * BATCH);   // 16 x 8 x 12; chamfer blocks use x<4
    partial_kernel<<<grid, BLK, 0, stream>>>(pred, gt, minseg, top4, hdr);
    merge_kernel<<<192, BLK, 0, stream>>>(minseg, top4, hdr, (float*)d_out);
}

// Round 5
// 97.011 us; speedup vs baseline: 1.1618x; 1.1618x over previous
//
#include <hip/hip_runtime.h>
#include <float.h>
#include <math.h>

#define BATCH 4
#define NPTS 4096
#define BLK 256
#define QCH 4                      // queries per thread (chamfer)
#define SEG_CH 32                  // chamfer target segments (128 pts each)
#define TPTS_CH (NPTS / SEG_CH)    // 128
#define SEG_R 8                    // repulsion target segments (512 pts each)
#define TPTS_R (NPTS / SEG_R)      // 512
#define H2 (0.03f * 0.03f)
#define RADIUS_C 0.07f
#define EPS_C 1e-12f
#define NQ (BATCH * NPTS)          // 16384
#define NCH (2 * NQ)               // 32768 chamfer (type,b,q) rows

// d_ws layout:
//   hdr    : float accum[2] + uint cnt + pad (16 B)   @ 0   (zeroed by blk(0,0))
//   minseg : float [SEG_CH][NCH]   (4 MB)             @ 16
//   top4   : float4[SEG_R][NQ]     (2 MB)             @ 16 + 4 MB
//
// d2 = (|t|^2 - 2 q.t) + |q|^2 (reference's own expansion); inner loops track
// h = |t|^2 - 2 q.t via n = -2q, +|q|^2 added at the partial store.
// R3 post-mortem: chamfer needs BOTH QCH=4 (16 VALU per ds_read_b128 broadcast
// -> VALU-bound) AND >=1024 blocks (R3's 256-block tail ran 1 wave/SIMD).

// grid = (128, 12): blockIdx.y = type*4 + b; type 0 pred->gt, 1 gt->pred, 2 rep.
// chamfer blocks: x = qblk(4) + 4*seg(32); repulsion: x = qblk(16) + 16*seg(8).
__global__ __launch_bounds__(BLK) void partial_kernel(
    const float* __restrict__ pred, const float* __restrict__ gt,
    float* __restrict__ minseg, float4* __restrict__ top4,
    unsigned int* __restrict__ hdr)
{
    __shared__ float4 s[TPTS_R];   // (x, y, z, |t|^2); chamfer uses first 128

    if (blockIdx.x == 0 && blockIdx.y == 0 && threadIdx.x < 4)
        hdr[threadIdx.x] = 0u;     // zero accum[2]+cnt for merge

    const int type = blockIdx.y >> 2;
    const int b    = blockIdx.y & 3;

    const float* qbase = (type == 1) ? gt : pred;
    const float* tbase = (type == 0) ? gt : pred;

    if (type < 2) {
        const int qblk = blockIdx.x & 3;
        const int seg  = blockIdx.x >> 2;
        // stage 128 targets: first wave, 2 points/thread, |t|^2 on the fly
        if (threadIdx.x < 64) {
            const float2* g2 = (const float2*)(tbase + ((size_t)b * NPTS + seg * TPTS_CH) * 3);
            float2 a = g2[3 * threadIdx.x + 0];
            float2 c = g2[3 * threadIdx.x + 1];
            float2 e = g2[3 * threadIdx.x + 2];
            float t20 = fmaf(a.x, a.x, fmaf(a.y, a.y, c.x * c.x));
            float t21 = fmaf(c.y, c.y, fmaf(e.x, e.x, e.y * e.y));
            s[2 * threadIdx.x + 0] = make_float4(a.x, a.y, c.x, t20);
            s[2 * threadIdx.x + 1] = make_float4(c.y, e.x, e.y, t21);
        }
        __syncthreads();

        const int q0 = qblk * (BLK * QCH) + threadIdx.x;
        float nx[QCH], ny[QCH], nz[QCH], q2[QCH], mn[QCH];
        #pragma unroll
        for (int k = 0; k < QCH; ++k) {
            const float* q = qbase + ((size_t)b * NPTS + q0 + k * BLK) * 3;
            float qx = q[0], qy = q[1], qz = q[2];
            q2[k] = fmaf(qx, qx, fmaf(qy, qy, qz * qz));
            nx[k] = -2.f * qx; ny[k] = -2.f * qy; nz[k] = -2.f * qz;
            mn[k] = FLT_MAX;
        }
        #pragma unroll 4
        for (int j = 0; j < TPTS_CH; ++j) {
            float4 t = s[j];
            #pragma unroll
            for (int k = 0; k < QCH; ++k)
                mn[k] = fminf(mn[k],
                    fmaf(nx[k], t.x, fmaf(ny[k], t.y, fmaf(nz[k], t.z, t.w))));
        }
        float* row = minseg + (size_t)seg * NCH + (type * BATCH + b) * NPTS;
        #pragma unroll
        for (int k = 0; k < QCH; ++k)
            row[q0 + k * BLK] = mn[k] + q2[k];
    } else {
        const int qblk = blockIdx.x & 15;
        const int seg  = blockIdx.x >> 4;
        // stage 512 targets: all threads, 2 points/thread
        {
            const float2* g2 = (const float2*)(tbase + ((size_t)b * NPTS + seg * TPTS_R) * 3);
            float2 a = g2[3 * threadIdx.x + 0];
            float2 c = g2[3 * threadIdx.x + 1];
            float2 e = g2[3 * threadIdx.x + 2];
            float t20 = fmaf(a.x, a.x, fmaf(a.y, a.y, c.x * c.x));
            float t21 = fmaf(c.y, c.y, fmaf(e.x, e.x, e.y * e.y));
            s[2 * threadIdx.x + 0] = make_float4(a.x, a.y, c.x, t20);
            s[2 * threadIdx.x + 1] = make_float4(c.y, e.x, e.y, t21);
        }
        __syncthreads();

        const int qi = qblk * BLK + threadIdx.x;
        const float* q = qbase + ((size_t)b * NPTS + qi) * 3;
        const float qx = q[0], qy = q[1], qz = q[2];
        const float q2 = fmaf(qx, qx, fmaf(qy, qy, qz * qz));
        const float nx = -2.f * qx, ny = -2.f * qy, nz = -2.f * qz;

        float m0 = FLT_MAX, m1 = FLT_MAX, m2 = FLT_MAX, m3 = FLT_MAX;
        const int base = seg * TPTS_R;
        #pragma unroll 4
        for (int j = 0; j < TPTS_R; ++j) {
            float4 t = s[j];
            float h = fmaf(nx, t.x, fmaf(ny, t.y, fmaf(nz, t.z, t.w)));
            h = (base + j == qi) ? FLT_MAX : h;            // exclude self
            float n0 = fminf(m0, h);  float u0 = fmaxf(m0, h);
            float n1 = fminf(m1, u0); float u1 = fmaxf(m1, u0);
            float n2 = fminf(m2, u1); float u2 = fmaxf(m2, u1);
            float n3 = fminf(m3, u2);
            m0 = n0; m1 = n1; m2 = n2; m3 = n3;
        }
        top4[(size_t)seg * NQ + b * NPTS + qi] =
            make_float4(m0 + q2, m1 + q2, m2 + q2, m3 + q2);
    }
}

// 192 blocks: [0,128) chamfer sum; [128,192) repulsion merge+eval.
// Last block (fenced atomic counter) finalizes both outputs.
__global__ __launch_bounds__(BLK) void merge_kernel(
    const float* __restrict__ minseg, const float4* __restrict__ top4,
    unsigned int* __restrict__ hdr, float* __restrict__ out)
{
    __shared__ float warr[BLK / 64];
    float contrib;
    int which;
    if (blockIdx.x < NCH / BLK) {
        int i = blockIdx.x * BLK + threadIdx.x;            // [0, 32768)
        float m = minseg[i];
        #pragma unroll
        for (int sg = 1; sg < SEG_CH; ++sg)
            m = fminf(m, minseg[(size_t)sg * NCH + i]);
        contrib = fmaxf(m, 0.f);                           // clamp as in reference
        which = 0;
    } else {
        int i = (blockIdx.x - NCH / BLK) * BLK + threadIdx.x;  // [0, 16384)
        float m0 = FLT_MAX, m1 = FLT_MAX, m2 = FLT_MAX, m3 = FLT_MAX;
        #pragma unroll
        for (int sg = 0; sg < SEG_R; ++sg) {
            float4 v = top4[(size_t)sg * NQ + i];
            const float vals[4] = {v.x, v.y, v.z, v.w};
            #pragma unroll
            for (int k = 0; k < 4; ++k) {
                float h = vals[k];
                float n0 = fminf(m0, h);  float u0 = fmaxf(m0, h);
                float n1 = fminf(m1, u0); float u1 = fmaxf(m1, u0);
                float n2 = fminf(m2, u1); float u2 = fmaxf(m2, u1);
                float n3 = fminf(m3, u2);
                m0 = n0; m1 = n1; m2 = n2; m3 = n3;
            }
        }
        contrib = 0.f;
        const float ms[4] = {m0, m1, m2, m3};
        #pragma unroll
        for (int k = 0; k < 4; ++k) {
            float d2 = fmaxf(ms[k], EPS_C);
            float d  = sqrtf(d2);
            contrib += (RADIUS_C - d) * expf(-d2 * (1.f / H2));
        }
        which = 1;
    }
    #pragma unroll
    for (int off = 32; off > 0; off >>= 1)
        contrib += __shfl_down(contrib, off, 64);
    if ((threadIdx.x & 63) == 0) warr[threadIdx.x >> 6] = contrib;
    __syncthreads();
    if (threadIdx.x == 0) {
        float bs = warr[0] + warr[1] + warr[2] + warr[3];
        float* accum = (float*)hdr;
        atomicAdd(&accum[which], bs);
        __threadfence();
        unsigned int old = atomicAdd(&hdr[2], 1u);
        if (old == 191u) {                                  // last block finalizes
            float a0 = atomicAdd(&accum[0], 0.f);           // coherent read
            float a1 = atomicAdd(&accum[1], 0.f);
            out[0] = 100.f * a0 * (1.f / NQ);
            out[1] = a1 * (1.f / (NQ * 4));
        }
    }
}

extern "C" void kernel_launch(void* const* d_in, const int* in_sizes, int n_in,
                              void* d_out, int out_size, void* d_ws, size_t ws_size,
                              hipStream_t stream)
{
    const float* pred = (const float*)d_in[0];
    const float* gt   = (const float*)d_in[1];

    unsigned int* hdr    = (unsigned int*)d_ws;
    float*        minseg = (float*)((char*)d_ws + 16);
    float4*       top4   = (float4*)((char*)d_ws + 16 + (size_t)SEG_CH * NCH * sizeof(float));

    dim3 grid(128, 3 * BATCH);   // 1536 blocks, all active
    partial_kernel<<<grid, BLK, 0, stream>>>(pred, gt, minseg, top4, hdr);
    merge_kernel<<<192, BLK, 0, stream>>>(minseg, top4, hdr, (float*)d_out);
}